// Round 7
// baseline (368.035 us; speedup 1.0000x reference)
//
#include <hip/hip_runtime.h>
#include <hip/hip_bf16.h>

#define NN 20000
#define NE 320000
#define NG 16
#define PSPLIT 32
#define NSCANB 79   // ceil(20000/256)
#define NHISTB 1250 // ceil(320000/256)

// ---------------- pack: edge histogram + layer-1 attention vectors ----------------
// blocks [0,1250): histogram of dst. blocks [1250,1253): wlr[j][k] = W1_h . a{l,r}_h

__global__ void pack_hist_wlr_kernel(const int* __restrict__ dst, int* __restrict__ indeg,
                                     const float* __restrict__ W1, const float* __restrict__ al1,
                                     const float* __restrict__ ar1, float* __restrict__ wlr) {
  int b = blockIdx.x, t = threadIdx.x;
  if (b < NHISTB) {
    int e = b * 256 + t;
    if (e < NE) atomicAdd(&indeg[dst[e]], 1);
  } else {
    int idx = (b - NHISTB) * 256 + t;  // 768 total
    if (idx >= 768) return;
    int k = idx & 127;
    int j = idx >> 7;  // 0..5
    int h = j % 3;
    const float* av = (j < 3 ? al1 : ar1) + h * 128;
    const float* wrow = W1 + (size_t)k * 384 + h * 128;
    float s = 0.f;
#pragma unroll 4
    for (int d = 0; d < 128; d++) s += wrow[d] * av[d];
    wlr[j * 128 + k] = s;
  }
}

// ---------------- pack: block-local scan of indeg + node attention coefs ----------------
// blocks [0,79): loc[i] = block-local exclusive scan, bsum[b] = block total
// blocks [79,5079): el1/er1 per node (one wave per node), reads wlr

__global__ void pack_scan1_elr_kernel(const int* __restrict__ indeg, int* __restrict__ loc,
                                      int* __restrict__ bsum, const float* __restrict__ x,
                                      const float* __restrict__ wlr, float* __restrict__ el,
                                      float* __restrict__ er) {
  __shared__ int ws[4];
  __shared__ float wl_s[768];
  int b = blockIdx.x, t = threadIdx.x;
  int lane = t & 63, wv = t >> 6;
  if (b < NSCANB) {
    int i = b * 256 + t;
    int v = (i < NN) ? indeg[i] : 0;
    int xx = v;
#pragma unroll
    for (int off = 1; off < 64; off <<= 1) {
      int y = __shfl_up(xx, off);
      if (lane >= off) xx += y;
    }
    if (lane == 63) ws[wv] = xx;
    __syncthreads();
    int add = 0;
    for (int w2 = 0; w2 < wv; w2++) add += ws[w2];
    xx += add;
    if (i < NN) loc[i] = xx - v;
    if (t == 255) bsum[b] = xx;
  } else {
    for (int i = t; i < 768; i += 256) wl_s[i] = wlr[i];
    __syncthreads();
    int w = ((b - NSCANB) * 256 + t) >> 6;
    if (w >= NN) return;
    float v0 = x[(size_t)w * 128 + lane], v1 = x[(size_t)w * 128 + 64 + lane];
    float s[6];
#pragma unroll
    for (int j = 0; j < 6; j++) s[j] = v0 * wl_s[j * 128 + lane] + v1 * wl_s[j * 128 + 64 + lane];
#pragma unroll
    for (int off = 32; off; off >>= 1)
#pragma unroll
      for (int j = 0; j < 6; j++) s[j] += __shfl_down(s[j], off);
    if (lane == 0) {
      el[w * 3 + 0] = s[0]; el[w * 3 + 1] = s[1]; el[w * 3 + 2] = s[2];
      er[w * 3 + 0] = s[3]; er[w * 3 + 1] = s[4]; er[w * 3 + 2] = s[5];
    }
  }
}

// scan block sums (nb <= 128), write offsets + grand total
__global__ void scan2_kernel(const int* __restrict__ bsum, int* __restrict__ boff,
                             int* __restrict__ rp_end, int nb) {
  int t = threadIdx.x;  // 128
  int lane = t & 63, wv = t >> 6;
  __shared__ int ws[2];
  int v = (t < nb) ? bsum[t] : 0;
  int x = v;
#pragma unroll
  for (int off = 1; off < 64; off <<= 1) {
    int y = __shfl_up(x, off);
    if (lane >= off) x += y;
  }
  if (lane == 63) ws[wv] = x;
  __syncthreads();
  if (wv == 1) x += ws[0];
  if (t < nb) boff[t] = x - v;
  if (t == 127) *rp_end = x;
}

// ---------------- pack: scatter edges into CSR + finalize rowptr ----------------
// blocks [0,1250): scatter (rowptr base computed inline as loc+boff)
// blocks [1250,1329): rowptr[i] = loc[i] + boff[i>>8]

__global__ void pack_scatter_fin_kernel(const int* __restrict__ src, const int* __restrict__ dst,
                                        const int* __restrict__ loc, const int* __restrict__ boff,
                                        int* __restrict__ cursor, int* __restrict__ csr_src,
                                        int* __restrict__ rowptr) {
  int b = blockIdx.x, t = threadIdx.x;
  if (b < NHISTB) {
    int e = b * 256 + t;
    if (e < NE) {
      int d = dst[e];
      int p = atomicAdd(&cursor[d], 1);
      csr_src[loc[d] + boff[d >> 8] + p] = src[e];
    }
  } else {
    int i = (b - NHISTB) * 256 + t;
    if (i < NN) rowptr[i] = loc[i] + boff[i >> 8];
  }
}

// ---------------- layer-1 aggregation in x-space ----------------

__global__ void aggregate_x_kernel(const float* __restrict__ x, const float* __restrict__ el,
                                   const float* __restrict__ er, const int* __restrict__ rowptr,
                                   const int* __restrict__ csr_src, float* __restrict__ aggx) {
  int n = blockIdx.x;
  int t = threadIdx.x;  // 128
  __shared__ float wbuf[3][128];
  __shared__ int sbuf[128];
  __shared__ float red[6];
  __shared__ float4 accbuf[3][4][32];
  int rs = rowptr[n];
  int deg = rowptr[n + 1] - rs;
  float er0 = er[n * 3 + 0], er1 = er[n * 3 + 1], er2 = er[n * 3 + 2];
  float p0 = 0.f, p1 = 0.f, p2 = 0.f;
  int g = t >> 5, dq = t & 31;
  const float* xd = x + dq * 4;
  float4 a0 = make_float4(0, 0, 0, 0), a1 = a0, a2 = a0;
  for (int base = 0; base < deg; base += 128) {
    int cnt = min(128, deg - base);
    if (t < cnt) {
      int s = csr_src[rs + base + t];
      sbuf[t] = s;
      float e0 = el[s * 3 + 0] + er0, e1 = el[s * 3 + 1] + er1, e2 = el[s * 3 + 2] + er2;
      e0 = e0 > 0.f ? e0 : 0.2f * e0;
      e1 = e1 > 0.f ? e1 : 0.2f * e1;
      e2 = e2 > 0.f ? e2 : 0.2f * e2;
      float w0 = __expf(e0), w1 = __expf(e1), w2 = __expf(e2);
      wbuf[0][t] = w0; wbuf[1][t] = w1; wbuf[2][t] = w2;
      p0 += w0; p1 += w1; p2 += w2;
    }
    __syncthreads();
    int j = g;
    for (; j + 4 < cnt; j += 8) {
      int s0 = sbuf[j], s1 = sbuf[j + 4];
      float4 v0 = *(const float4*)(xd + (size_t)s0 * 128);
      float4 v1 = *(const float4*)(xd + (size_t)s1 * 128);
      float w00 = wbuf[0][j], w01 = wbuf[1][j], w02 = wbuf[2][j];
      float w10 = wbuf[0][j + 4], w11 = wbuf[1][j + 4], w12 = wbuf[2][j + 4];
      a0.x += w00 * v0.x + w10 * v1.x; a0.y += w00 * v0.y + w10 * v1.y;
      a0.z += w00 * v0.z + w10 * v1.z; a0.w += w00 * v0.w + w10 * v1.w;
      a1.x += w01 * v0.x + w11 * v1.x; a1.y += w01 * v0.y + w11 * v1.y;
      a1.z += w01 * v0.z + w11 * v1.z; a1.w += w01 * v0.w + w11 * v1.w;
      a2.x += w02 * v0.x + w12 * v1.x; a2.y += w02 * v0.y + w12 * v1.y;
      a2.z += w02 * v0.z + w12 * v1.z; a2.w += w02 * v0.w + w12 * v1.w;
    }
    for (; j < cnt; j += 4) {
      int s = sbuf[j];
      float4 v = *(const float4*)(xd + (size_t)s * 128);
      float w0 = wbuf[0][j], w1 = wbuf[1][j], w2 = wbuf[2][j];
      a0.x += w0 * v.x; a0.y += w0 * v.y; a0.z += w0 * v.z; a0.w += w0 * v.w;
      a1.x += w1 * v.x; a1.y += w1 * v.y; a1.z += w1 * v.z; a1.w += w1 * v.w;
      a2.x += w2 * v.x; a2.y += w2 * v.y; a2.z += w2 * v.z; a2.w += w2 * v.w;
    }
    __syncthreads();
  }
  for (int off = 32; off; off >>= 1) {
    p0 += __shfl_down(p0, off);
    p1 += __shfl_down(p1, off);
    p2 += __shfl_down(p2, off);
  }
  int wv = t >> 6, ln = t & 63;
  if (ln == 0) { red[wv * 3 + 0] = p0; red[wv * 3 + 1] = p1; red[wv * 3 + 2] = p2; }
  accbuf[0][g][dq] = a0;
  accbuf[1][g][dq] = a1;
  accbuf[2][g][dq] = a2;
  __syncthreads();
  if (t < 96) {
    int h = t >> 5, d = t & 31;
    float4 s0 = accbuf[h][0][d], s1 = accbuf[h][1][d], s2 = accbuf[h][2][d], s3 = accbuf[h][3][d];
    float dn = red[h] + red[3 + h];
    float inv = dn > 0.f ? 1.f / dn : 0.f;
    float4 r;
    r.x = (s0.x + s1.x + s2.x + s3.x) * inv;
    r.y = (s0.y + s1.y + s2.y + s3.y) * inv;
    r.z = (s0.z + s1.z + s2.z + s3.z) * inv;
    r.w = (s0.w + s1.w + s2.w + s3.w) * inv;
    *(float4*)&aggx[(size_t)n * 384 + h * 128 + d * 4] = r;
  }
}

// ---------------- GEMM: A from LDS, B from global (L1/L2-resident weights) ----------------
// Block 128 threads, tile 32 rows x (32*R) cols; per-thread R rows x 8 cols.
// R=4: cols=128 (tm 0..7); R=2: cols=64 (tm 0..15). 20000 = 625*32 -> no bounds checks.
// LDS per k-step: one small A-frag read per thread (b128/b64); B-frag = 2 global
// float4 loads hitting L1 (8KB B-slice per k0-tile). Compute-bound by design.

template <int K, int R, bool HEADS, bool BIAS_ELU>
__launch_bounds__(128)
__global__ void gemm_bg_kernel(const float* __restrict__ A, int lda,
                               const float* __restrict__ B, int ldb,
                               float* __restrict__ C, int ldc,
                               const float* __restrict__ bias) {
  __shared__ float As[32 * 36];  // [k][m], pad 36
  constexpr int TM = 32 / R;     // thread-rows
  int t = threadIdx.x;
  int m0 = blockIdx.x * 32;
  int col0 = blockIdx.y * (32 * R);
  if (HEADS) A += col0;  // head's K-slice of aggx
  int tm = t / (128 / TM);       // 0..TM-1
  int tn = t % (128 / TM);       // 0..(128/TM)-1, 8 cols each
  const float* Bp = B + col0 + tn * 8;
  float acc[R][8];
#pragma unroll
  for (int i = 0; i < R; i++)
#pragma unroll
    for (int j = 0; j < 8; j++) acc[i][j] = 0.f;

  for (int k0 = 0; k0 < K; k0 += 32) {
    // stage A 32 rows x 32 k, transposed into As[k][m]
#pragma unroll
    for (int i = 0; i < 2; i++) {
      int idx = t + i * 128;
      int r = idx >> 3, kq = (idx & 7) * 4;
      float4 v = *(const float4*)&A[(size_t)(m0 + r) * lda + k0 + kq];
      As[(kq + 0) * 36 + r] = v.x;
      As[(kq + 1) * 36 + r] = v.y;
      As[(kq + 2) * 36 + r] = v.z;
      As[(kq + 3) * 36 + r] = v.w;
    }
    __syncthreads();
#pragma unroll 8
    for (int k = 0; k < 32; k++) {
      const float* brow = Bp + (size_t)(k0 + k) * ldb;
      float4 b0 = *(const float4*)brow;
      float4 b1 = *(const float4*)(brow + 4);
      float bf[8] = {b0.x, b0.y, b0.z, b0.w, b1.x, b1.y, b1.z, b1.w};
      float af[R];
#pragma unroll
      for (int i = 0; i < R; i++) af[i] = As[k * 36 + tm * R + i];
#pragma unroll
      for (int i = 0; i < R; i++)
#pragma unroll
        for (int j = 0; j < 8; j++) acc[i][j] += af[i] * bf[j];
    }
    __syncthreads();
  }
  float bv[8];
  if (BIAS_ELU) {
#pragma unroll
    for (int j = 0; j < 8; j++) bv[j] = bias[col0 + tn * 8 + j];
  }
#pragma unroll
  for (int i = 0; i < R; i++) {
    int gm = m0 + tm * R + i;
    float r[8];
#pragma unroll
    for (int j = 0; j < 8; j++) {
      float v = acc[i][j];
      if (BIAS_ELU) {
        v += bv[j];
        v = v > 0.f ? v : expm1f(v);
      }
      r[j] = v;
    }
    *(float4*)&C[(size_t)gm * ldc + col0 + tn * 8] = make_float4(r[0], r[1], r[2], r[3]);
    *(float4*)&C[(size_t)gm * ldc + col0 + tn * 8 + 4] = make_float4(r[4], r[5], r[6], r[7]);
  }
}

// ---------------- attention coefficients (layer 2, H=1, reads f2) ----------------

__global__ void att_coef_kernel(const float* __restrict__ f, const float* __restrict__ al,
                                const float* __restrict__ ar, float* __restrict__ el,
                                float* __restrict__ er, int NH) {
  int w = (blockIdx.x * 256 + threadIdx.x) >> 6;
  int lane = threadIdx.x & 63;
  if (w >= NH) return;
  const float* fr = f + (size_t)w * 128;
  float v0 = fr[lane], v1 = fr[64 + lane];
  float a0 = al[lane], a1 = al[64 + lane];
  float r0 = ar[lane], r1 = ar[64 + lane];
  float se = v0 * a0 + v1 * a1;
  float sr = v0 * r0 + v1 * r1;
  for (int off = 32; off; off >>= 1) {
    se += __shfl_down(se, off);
    sr += __shfl_down(sr, off);
  }
  if (lane == 0) { el[w] = se; er[w] = sr; }
}

// ---------------- layer-2 aggregation (H=1, gathers f2) ----------------

__global__ void aggregate1_kernel(const float* __restrict__ f, const float* __restrict__ el,
                                  const float* __restrict__ er, const float* __restrict__ bias,
                                  const int* __restrict__ rowptr, const int* __restrict__ csr_src,
                                  float* __restrict__ out) {
  int n = blockIdx.x;
  int t = threadIdx.x;
  __shared__ float wbuf[128];
  __shared__ int sbuf[128];
  __shared__ float red[2];
  __shared__ float4 accbuf[4][32];
  int rs = rowptr[n];
  int deg = rowptr[n + 1] - rs;
  float ern = er[n];
  float psum = 0.f;
  int g = t >> 5;
  int d = (t & 31) * 4;
  const float* fd = f + d;
  float4 acc = make_float4(0.f, 0.f, 0.f, 0.f);
  for (int base = 0; base < deg; base += 128) {
    int cnt = min(128, deg - base);
    if (t < cnt) {
      int s = csr_src[rs + base + t];
      sbuf[t] = s;
      float e = el[s] + ern;
      e = e > 0.f ? e : 0.2f * e;
      float w = __expf(e);
      wbuf[t] = w;
      psum += w;
    }
    __syncthreads();
    int j = g;
    for (; j + 4 < cnt; j += 8) {
      int s0 = sbuf[j], s1 = sbuf[j + 4];
      float4 v0 = *(const float4*)(fd + (size_t)s0 * 128);
      float4 v1 = *(const float4*)(fd + (size_t)s1 * 128);
      float w0 = wbuf[j], w1 = wbuf[j + 4];
      acc.x += w0 * v0.x + w1 * v1.x;
      acc.y += w0 * v0.y + w1 * v1.y;
      acc.z += w0 * v0.z + w1 * v1.z;
      acc.w += w0 * v0.w + w1 * v1.w;
    }
    for (; j < cnt; j += 4) {
      int s = sbuf[j];
      float4 v = *(const float4*)(fd + (size_t)s * 128);
      float w = wbuf[j];
      acc.x += w * v.x; acc.y += w * v.y; acc.z += w * v.z; acc.w += w * v.w;
    }
    __syncthreads();
  }
  for (int off = 32; off; off >>= 1) psum += __shfl_down(psum, off);
  int wv = t >> 6, ln = t & 63;
  if (ln == 0) red[wv] = psum;
  accbuf[g][t & 31] = acc;
  __syncthreads();
  if (t < 32) {
    float4 a0 = accbuf[0][t], a1 = accbuf[1][t], a2 = accbuf[2][t], a3 = accbuf[3][t];
    float dn = red[0] + red[1];
    float inv = dn > 0.f ? 1.f / dn : 0.f;
    const float* bp = bias + t * 4;
    float4 r;
    r.x = (a0.x + a1.x + a2.x + a3.x) * inv + bp[0];
    r.y = (a0.y + a1.y + a2.y + a3.y) * inv + bp[1];
    r.z = (a0.z + a1.z + a2.z + a3.z) * inv + bp[2];
    r.w = (a0.w + a1.w + a2.w + a3.w) * inv + bp[3];
    *(float4*)&out[(size_t)n * 128 + t * 4] = r;
  }
}

// ---------------- mean-pool: 2-stage ----------------

__global__ void pool_partial_kernel(const float* __restrict__ h2, const int* __restrict__ gid,
                                    float* __restrict__ sums, int N) {
  int g = blockIdx.x / PSPLIT;
  int sp = blockIdx.x % PSPLIT;
  int tid = threadIdx.x;
  int lo0 = 0, hi0 = N;
  while (lo0 < hi0) { int m = (lo0 + hi0) >> 1; if (gid[m] < g) lo0 = m + 1; else hi0 = m; }
  int lo1 = lo0, hi1 = N;
  while (lo1 < hi1) { int m = (lo1 + hi1) >> 1; if (gid[m] < g + 1) lo1 = m + 1; else hi1 = m; }
  float a0 = 0.f, a1 = 0.f, a2 = 0.f, a3 = 0.f;
  int n = lo0 + sp;
  for (; n + 3 * PSPLIT < lo1; n += 4 * PSPLIT) {
    a0 += h2[(size_t)n * 128 + tid];
    a1 += h2[(size_t)(n + PSPLIT) * 128 + tid];
    a2 += h2[(size_t)(n + 2 * PSPLIT) * 128 + tid];
    a3 += h2[(size_t)(n + 3 * PSPLIT) * 128 + tid];
  }
  for (; n < lo1; n += PSPLIT) a0 += h2[(size_t)n * 128 + tid];
  float acc = (a0 + a1) + (a2 + a3);
  atomicAdd(&sums[g * 128 + tid], acc);
}

__global__ void pool_final_kernel(const float* __restrict__ sums, const int* __restrict__ gid,
                                  const float* __restrict__ linW, const float* __restrict__ linb,
                                  float* __restrict__ out, int N) {
  int g = blockIdx.x;
  int tid = threadIdx.x;
  int lo0 = 0, hi0 = N;
  while (lo0 < hi0) { int m = (lo0 + hi0) >> 1; if (gid[m] < g) lo0 = m + 1; else hi0 = m; }
  int lo1 = lo0, hi1 = N;
  while (lo1 < hi1) { int m = (lo1 + hi1) >> 1; if (gid[m] < g + 1) lo1 = m + 1; else hi1 = m; }
  int cnt = lo1 - lo0;
  float hg = sums[g * 128 + tid] / (float)(cnt > 0 ? cnt : 1);
  __shared__ float hgs[128];
  hgs[tid] = hg;
  __syncthreads();
  float o = linb[tid];
#pragma unroll 4
  for (int dd = 0; dd < 128; dd++) o += hgs[dd] * linW[dd * 128 + tid];
  out[g * 128 + tid] = fmaxf(o, 0.f);
}

// ---------------- launch ----------------

extern "C" void kernel_launch(void* const* d_in, const int* in_sizes, int n_in,
                              void* d_out, int out_size, void* d_ws, size_t ws_size,
                              hipStream_t stream) {
  const float* x    = (const float*)d_in[0];
  const int*   src  = (const int*)d_in[1];
  const int*   dst  = (const int*)d_in[2];
  const int*   gid  = (const int*)d_in[3];
  const float* W1   = (const float*)d_in[4];
  const float* al1  = (const float*)d_in[5];
  const float* ar1  = (const float*)d_in[6];
  const float* b1   = (const float*)d_in[7];
  const float* W2   = (const float*)d_in[8];
  const float* al2  = (const float*)d_in[9];
  const float* ar2  = (const float*)d_in[10];
  const float* b2   = (const float*)d_in[11];
  const float* linW = (const float*)d_in[12];
  const float* linb = (const float*)d_in[13];
  float* out = (float*)d_out;

  char* ws = (char*)d_ws;
  size_t off = 0;
  auto alloc = [&](size_t bytes) -> void* {
    void* p = ws + off;
    off += (bytes + 255) & ~(size_t)255;
    return p;
  };
  float* aggx    = (float*)alloc((size_t)NN * 384 * 4);
  float* h1      = (float*)alloc((size_t)NN * 384 * 4);
  float* f2      = (float*)alloc((size_t)NN * 128 * 4);
  float* h2      = (float*)alloc((size_t)NN * 128 * 4);
  float* el1     = (float*)alloc((size_t)NN * 3 * 4);
  float* er1     = (float*)alloc((size_t)NN * 3 * 4);
  float* el2     = (float*)alloc((size_t)NN * 4);
  float* er2     = (float*)alloc((size_t)NN * 4);
  float* wlr     = (float*)alloc((size_t)768 * 4);
  int*   loc     = (int*)alloc((size_t)NN * 4);
  int*   rowptr  = (int*)alloc((size_t)(NN + 1) * 4);
  int*   csr_src = (int*)alloc((size_t)NE * 4);
  int*   bsum    = (int*)alloc((size_t)NSCANB * 4);
  int*   boff    = (int*)alloc((size_t)NSCANB * 4);
  // zero-initialized region (single memset): indeg, cursor, gsums
  int*   indeg   = (int*)alloc((size_t)NN * 4);
  int*   cursor  = (int*)alloc((size_t)NN * 4);
  float* gsums   = (float*)alloc((size_t)NG * 128 * 4);
  (void)ws_size;
  size_t zbytes = (char*)(gsums + NG * 128) - (char*)indeg;
  hipMemsetAsync(indeg, 0, zbytes, stream);

  // CSR build + layer-1 attention coefs (packed)
  pack_hist_wlr_kernel<<<NHISTB + 3, 256, 0, stream>>>(dst, indeg, W1, al1, ar1, wlr);
  pack_scan1_elr_kernel<<<NSCANB + 5000, 256, 0, stream>>>(indeg, loc, bsum, x, wlr, el1, er1);
  scan2_kernel<<<1, 128, 0, stream>>>(bsum, boff, rowptr + NN, NSCANB);
  pack_scatter_fin_kernel<<<NHISTB + NSCANB, 256, 0, stream>>>(src, dst, loc, boff, cursor,
                                                               csr_src, rowptr);

  // Layer 1 (x-space): aggregate x -> per-head GEMM with bias+ELU
  aggregate_x_kernel<<<NN, 128, 0, stream>>>(x, el1, er1, rowptr, csr_src, aggx);
  gemm_bg_kernel<128, 4, true, true><<<dim3(625, 3), 128, 0, stream>>>(
      aggx, 384, W1, 384, h1, 384, b1);

  // Layer 2: f2 = h1 @ W2 ; el2/er2 ; aggregate(+b2) -> h2
  gemm_bg_kernel<384, 2, false, false><<<dim3(625, 2), 128, 0, stream>>>(
      h1, 384, W2, 128, f2, 128, nullptr);
  att_coef_kernel<<<5000, 256, 0, stream>>>(f2, al2, ar2, el2, er2, NN);
  aggregate1_kernel<<<NN, 128, 0, stream>>>(f2, el2, er2, b2, rowptr, csr_src, h2);

  // Mean-pool + linear head
  pool_partial_kernel<<<NG * PSPLIT, 128, 0, stream>>>(h2, gid, gsums, NN);
  pool_final_kernel<<<NG, 128, 0, stream>>>(gsums, gid, linW, linb, out, NN);
}

// Round 8
// 300.125 us; speedup vs baseline: 1.2263x; 1.2263x over previous
//
#include <hip/hip_runtime.h>
#include <hip/hip_bf16.h>

#define NN 20000
#define NE 320000
#define NG 16
#define PSPLIT 32
#define NSCANB 79   // ceil(20000/256)
#define NHISTB 1250 // ceil(320000/256)

// ---------------- pack: edge histogram + layer-1 attention vectors ----------------

__global__ void pack_hist_wlr_kernel(const int* __restrict__ dst, int* __restrict__ indeg,
                                     const float* __restrict__ W1, const float* __restrict__ al1,
                                     const float* __restrict__ ar1, float* __restrict__ wlr) {
  int b = blockIdx.x, t = threadIdx.x;
  if (b < NHISTB) {
    int e = b * 256 + t;
    if (e < NE) atomicAdd(&indeg[dst[e]], 1);
  } else {
    int idx = (b - NHISTB) * 256 + t;  // 768 total
    if (idx >= 768) return;
    int k = idx & 127;
    int j = idx >> 7;  // 0..5
    int h = j % 3;
    const float* av = (j < 3 ? al1 : ar1) + h * 128;
    const float* wrow = W1 + (size_t)k * 384 + h * 128;
    float s = 0.f;
#pragma unroll 4
    for (int d = 0; d < 128; d++) s += wrow[d] * av[d];
    wlr[j * 128 + k] = s;
  }
}

// ---------------- pack: block-local scan of indeg + layer-1 node coefs ----------------

__global__ void pack_scan1_elr_kernel(const int* __restrict__ indeg, int* __restrict__ loc,
                                      int* __restrict__ bsum, const float* __restrict__ x,
                                      const float* __restrict__ wlr, float* __restrict__ el,
                                      float* __restrict__ er) {
  __shared__ int ws[4];
  __shared__ float wl_s[768];
  int b = blockIdx.x, t = threadIdx.x;
  int lane = t & 63, wv = t >> 6;
  if (b < NSCANB) {
    int i = b * 256 + t;
    int v = (i < NN) ? indeg[i] : 0;
    int xx = v;
#pragma unroll
    for (int off = 1; off < 64; off <<= 1) {
      int y = __shfl_up(xx, off);
      if (lane >= off) xx += y;
    }
    if (lane == 63) ws[wv] = xx;
    __syncthreads();
    int add = 0;
    for (int w2 = 0; w2 < wv; w2++) add += ws[w2];
    xx += add;
    if (i < NN) loc[i] = xx - v;
    if (t == 255) bsum[b] = xx;
  } else {
    for (int i = t; i < 768; i += 256) wl_s[i] = wlr[i];
    __syncthreads();
    int w = ((b - NSCANB) * 256 + t) >> 6;
    if (w >= NN) return;
    float v0 = x[(size_t)w * 128 + lane], v1 = x[(size_t)w * 128 + 64 + lane];
    float s[6];
#pragma unroll
    for (int j = 0; j < 6; j++) s[j] = v0 * wl_s[j * 128 + lane] + v1 * wl_s[j * 128 + 64 + lane];
#pragma unroll
    for (int off = 32; off; off >>= 1)
#pragma unroll
      for (int j = 0; j < 6; j++) s[j] += __shfl_down(s[j], off);
    if (lane == 0) {
      el[w * 3 + 0] = s[0]; el[w * 3 + 1] = s[1]; el[w * 3 + 2] = s[2];
      er[w * 3 + 0] = s[3]; er[w * 3 + 1] = s[4]; er[w * 3 + 2] = s[5];
    }
  }
}

__global__ void scan2_kernel(const int* __restrict__ bsum, int* __restrict__ boff,
                             int* __restrict__ rp_end, int nb) {
  int t = threadIdx.x;  // 128
  int lane = t & 63, wv = t >> 6;
  __shared__ int ws[2];
  int v = (t < nb) ? bsum[t] : 0;
  int x = v;
#pragma unroll
  for (int off = 1; off < 64; off <<= 1) {
    int y = __shfl_up(x, off);
    if (lane >= off) x += y;
  }
  if (lane == 63) ws[wv] = x;
  __syncthreads();
  if (wv == 1) x += ws[0];
  if (t < nb) boff[t] = x - v;
  if (t == 127) *rp_end = x;
}

__global__ void pack_scatter_fin_kernel(const int* __restrict__ src, const int* __restrict__ dst,
                                        const int* __restrict__ loc, const int* __restrict__ boff,
                                        int* __restrict__ cursor, int* __restrict__ csr_src,
                                        int* __restrict__ rowptr) {
  int b = blockIdx.x, t = threadIdx.x;
  if (b < NHISTB) {
    int e = b * 256 + t;
    if (e < NE) {
      int d = dst[e];
      int p = atomicAdd(&cursor[d], 1);
      csr_src[loc[d] + boff[d >> 8] + p] = src[e];
    }
  } else {
    int i = (b - NHISTB) * 256 + t;
    if (i < NN) rowptr[i] = loc[i] + boff[i >> 8];
  }
}

// ---------------- layer-1 aggregation in x-space ----------------

__global__ void aggregate_x_kernel(const float* __restrict__ x, const float* __restrict__ el,
                                   const float* __restrict__ er, const int* __restrict__ rowptr,
                                   const int* __restrict__ csr_src, float* __restrict__ aggx) {
  int n = blockIdx.x;
  int t = threadIdx.x;  // 128
  __shared__ float wbuf[3][128];
  __shared__ int sbuf[128];
  __shared__ float red[6];
  __shared__ float4 accbuf[3][4][32];
  int rs = rowptr[n];
  int deg = rowptr[n + 1] - rs;
  float er0 = er[n * 3 + 0], er1 = er[n * 3 + 1], er2 = er[n * 3 + 2];
  float p0 = 0.f, p1 = 0.f, p2 = 0.f;
  int g = t >> 5, dq = t & 31;
  const float* xd = x + dq * 4;
  float4 a0 = make_float4(0, 0, 0, 0), a1 = a0, a2 = a0;
  for (int base = 0; base < deg; base += 128) {
    int cnt = min(128, deg - base);
    if (t < cnt) {
      int s = csr_src[rs + base + t];
      sbuf[t] = s;
      float e0 = el[s * 3 + 0] + er0, e1 = el[s * 3 + 1] + er1, e2 = el[s * 3 + 2] + er2;
      e0 = e0 > 0.f ? e0 : 0.2f * e0;
      e1 = e1 > 0.f ? e1 : 0.2f * e1;
      e2 = e2 > 0.f ? e2 : 0.2f * e2;
      float w0 = __expf(e0), w1 = __expf(e1), w2 = __expf(e2);
      wbuf[0][t] = w0; wbuf[1][t] = w1; wbuf[2][t] = w2;
      p0 += w0; p1 += w1; p2 += w2;
    }
    __syncthreads();
    int j = g;
    for (; j + 4 < cnt; j += 8) {
      int s0 = sbuf[j], s1 = sbuf[j + 4];
      float4 v0 = *(const float4*)(xd + (size_t)s0 * 128);
      float4 v1 = *(const float4*)(xd + (size_t)s1 * 128);
      float w00 = wbuf[0][j], w01 = wbuf[1][j], w02 = wbuf[2][j];
      float w10 = wbuf[0][j + 4], w11 = wbuf[1][j + 4], w12 = wbuf[2][j + 4];
      a0.x += w00 * v0.x + w10 * v1.x; a0.y += w00 * v0.y + w10 * v1.y;
      a0.z += w00 * v0.z + w10 * v1.z; a0.w += w00 * v0.w + w10 * v1.w;
      a1.x += w01 * v0.x + w11 * v1.x; a1.y += w01 * v0.y + w11 * v1.y;
      a1.z += w01 * v0.z + w11 * v1.z; a1.w += w01 * v0.w + w11 * v1.w;
      a2.x += w02 * v0.x + w12 * v1.x; a2.y += w02 * v0.y + w12 * v1.y;
      a2.z += w02 * v0.z + w12 * v1.z; a2.w += w02 * v0.w + w12 * v1.w;
    }
    for (; j < cnt; j += 4) {
      int s = sbuf[j];
      float4 v = *(const float4*)(xd + (size_t)s * 128);
      float w0 = wbuf[0][j], w1 = wbuf[1][j], w2 = wbuf[2][j];
      a0.x += w0 * v.x; a0.y += w0 * v.y; a0.z += w0 * v.z; a0.w += w0 * v.w;
      a1.x += w1 * v.x; a1.y += w1 * v.y; a1.z += w1 * v.z; a1.w += w1 * v.w;
      a2.x += w2 * v.x; a2.y += w2 * v.y; a2.z += w2 * v.z; a2.w += w2 * v.w;
    }
    __syncthreads();
  }
  for (int off = 32; off; off >>= 1) {
    p0 += __shfl_down(p0, off);
    p1 += __shfl_down(p1, off);
    p2 += __shfl_down(p2, off);
  }
  int wv = t >> 6, ln = t & 63;
  if (ln == 0) { red[wv * 3 + 0] = p0; red[wv * 3 + 1] = p1; red[wv * 3 + 2] = p2; }
  accbuf[0][g][dq] = a0;
  accbuf[1][g][dq] = a1;
  accbuf[2][g][dq] = a2;
  __syncthreads();
  if (t < 96) {
    int h = t >> 5, d = t & 31;
    float4 s0 = accbuf[h][0][d], s1 = accbuf[h][1][d], s2 = accbuf[h][2][d], s3 = accbuf[h][3][d];
    float dn = red[h] + red[3 + h];
    float inv = dn > 0.f ? 1.f / dn : 0.f;
    float4 r;
    r.x = (s0.x + s1.x + s2.x + s3.x) * inv;
    r.y = (s0.y + s1.y + s2.y + s3.y) * inv;
    r.z = (s0.z + s1.z + s2.z + s3.z) * inv;
    r.w = (s0.w + s1.w + s2.w + s3.w) * inv;
    *(float4*)&aggx[(size_t)n * 384 + h * 128 + d * 4] = r;
  }
}

// ---------------- GEMM: 32x64 tile, 128 threads, K staged in 128-chunks ----------------
// As[k][40] transposed (staging writes 2-way free; a-frag b128 broadcast-free),
// Bs[k][64] (all 2-way). 2 barriers per 128 k-steps; 53KB LDS -> 3 blocks/CU.
// 20000 = 625*32 -> no bounds checks. HEADS: A k-slice = head*128 (col0>>7).
// EL2: epilogue computes el2/er2 partial dots and atomicAdds (el2/er2 pre-zeroed).

template <int KT, bool HEADS, bool BIAS_ELU, bool EL2>
__launch_bounds__(128)
__global__ void gemm_k128_kernel(const float* __restrict__ A, int lda,
                                 const float* __restrict__ B, int ldb,
                                 float* __restrict__ C, int ldc,
                                 const float* __restrict__ bias,
                                 const float* __restrict__ al2, const float* __restrict__ ar2,
                                 float* __restrict__ el2, float* __restrict__ er2) {
  __shared__ float As[128 * 40];
  __shared__ float Bs[128 * 64];
  int t = threadIdx.x;
  int m0 = blockIdx.x * 32;
  int col0 = blockIdx.y * 64;
  if (HEADS) A += (col0 >> 7) * 128;
  int tm = t >> 4, tn = t & 15;  // tm 0..7 (rows tm*4..+3), tn 0..15 (cols col0+tn*4..+3)
  float acc[4][4];
#pragma unroll
  for (int i = 0; i < 4; i++)
#pragma unroll
    for (int j = 0; j < 4; j++) acc[i][j] = 0.f;

  for (int k0 = 0; k0 < KT; k0 += 128) {
    // stage A: 32 rows x 128 k, transposed. thread row = idx&31 -> write bank 2-way.
#pragma unroll
    for (int j = 0; j < 8; j++) {
      int idx = t + j * 128;
      int r = idx & 31, kq = (idx >> 5) * 4;
      float4 v = *(const float4*)&A[(size_t)(m0 + r) * lda + k0 + kq];
      As[(kq + 0) * 40 + r] = v.x;
      As[(kq + 1) * 40 + r] = v.y;
      As[(kq + 2) * 40 + r] = v.z;
      As[(kq + 3) * 40 + r] = v.w;
    }
    // stage B: 128 k x 64 n, coalesced global, 2-way LDS writes
#pragma unroll
    for (int j = 0; j < 16; j++) {
      int idx = t + j * 128;
      int kk = idx >> 4, nq = (idx & 15) * 4;
      *(float4*)&Bs[kk * 64 + nq] = *(const float4*)&B[(size_t)(k0 + kk) * ldb + col0 + nq];
    }
    __syncthreads();
#pragma unroll 8
    for (int k = 0; k < 128; k++) {
      float4 a = *(const float4*)&As[k * 40 + tm * 4];
      float4 b = *(const float4*)&Bs[k * 64 + tn * 4];
      float af[4] = {a.x, a.y, a.z, a.w};
      float bf[4] = {b.x, b.y, b.z, b.w};
#pragma unroll
      for (int i = 0; i < 4; i++)
#pragma unroll
        for (int j = 0; j < 4; j++) acc[i][j] += af[i] * bf[j];
    }
    __syncthreads();
  }
  // epilogue: store C (+bias/ELU for layer-1)
  float bv[4];
  if (BIAS_ELU) {
#pragma unroll
    for (int j = 0; j < 4; j++) bv[j] = bias[col0 + tn * 4 + j];
  }
#pragma unroll
  for (int i = 0; i < 4; i++) {
    int gm = m0 + tm * 4 + i;
    float r[4];
#pragma unroll
    for (int j = 0; j < 4; j++) {
      float v = acc[i][j];
      if (BIAS_ELU) {
        v += bv[j];
        v = v > 0.f ? v : expm1f(v);
      }
      r[j] = v;
    }
    *(float4*)&C[(size_t)gm * ldc + col0 + tn * 4] = make_float4(r[0], r[1], r[2], r[3]);
  }
  if (EL2) {
    // partial attention dots over this block's 64 cols; reduce via LDS, atomicAdd out
    float av[4], rv[4];
#pragma unroll
    for (int j = 0; j < 4; j++) { av[j] = al2[col0 + tn * 4 + j]; rv[j] = ar2[col0 + tn * 4 + j]; }
    __syncthreads();  // done with As; reuse as reduction buffer [32 rows][16 tn][2]
    float* red = As;
#pragma unroll
    for (int i = 0; i < 4; i++) {
      float pe = acc[i][0] * av[0] + acc[i][1] * av[1] + acc[i][2] * av[2] + acc[i][3] * av[3];
      float pr = acc[i][0] * rv[0] + acc[i][1] * rv[1] + acc[i][2] * rv[2] + acc[i][3] * rv[3];
      red[(tm * 4 + i) * 32 + tn * 2 + 0] = pe;
      red[(tm * 4 + i) * 32 + tn * 2 + 1] = pr;
    }
    __syncthreads();
    if (t < 32) {
      float se = 0.f, sr = 0.f;
#pragma unroll
      for (int q = 0; q < 16; q++) { se += red[t * 32 + 2 * q]; sr += red[t * 32 + 2 * q + 1]; }
      atomicAdd(&el2[m0 + t], se);
      atomicAdd(&er2[m0 + t], sr);
    }
  }
}

// ---------------- layer-2 aggregation (H=1, gathers f2) ----------------

__global__ void aggregate1_kernel(const float* __restrict__ f, const float* __restrict__ el,
                                  const float* __restrict__ er, const float* __restrict__ bias,
                                  const int* __restrict__ rowptr, const int* __restrict__ csr_src,
                                  float* __restrict__ out) {
  int n = blockIdx.x;
  int t = threadIdx.x;
  __shared__ float wbuf[128];
  __shared__ int sbuf[128];
  __shared__ float red[2];
  __shared__ float4 accbuf[4][32];
  int rs = rowptr[n];
  int deg = rowptr[n + 1] - rs;
  float ern = er[n];
  float psum = 0.f;
  int g = t >> 5;
  int d = (t & 31) * 4;
  const float* fd = f + d;
  float4 acc = make_float4(0.f, 0.f, 0.f, 0.f);
  for (int base = 0; base < deg; base += 128) {
    int cnt = min(128, deg - base);
    if (t < cnt) {
      int s = csr_src[rs + base + t];
      sbuf[t] = s;
      float e = el[s] + ern;
      e = e > 0.f ? e : 0.2f * e;
      float w = __expf(e);
      wbuf[t] = w;
      psum += w;
    }
    __syncthreads();
    int j = g;
    for (; j + 4 < cnt; j += 8) {
      int s0 = sbuf[j], s1 = sbuf[j + 4];
      float4 v0 = *(const float4*)(fd + (size_t)s0 * 128);
      float4 v1 = *(const float4*)(fd + (size_t)s1 * 128);
      float w0 = wbuf[j], w1 = wbuf[j + 4];
      acc.x += w0 * v0.x + w1 * v1.x;
      acc.y += w0 * v0.y + w1 * v1.y;
      acc.z += w0 * v0.z + w1 * v1.z;
      acc.w += w0 * v0.w + w1 * v1.w;
    }
    for (; j < cnt; j += 4) {
      int s = sbuf[j];
      float4 v = *(const float4*)(fd + (size_t)s * 128);
      float w = wbuf[j];
      acc.x += w * v.x; acc.y += w * v.y; acc.z += w * v.z; acc.w += w * v.w;
    }
    __syncthreads();
  }
  for (int off = 32; off; off >>= 1) psum += __shfl_down(psum, off);
  int wv = t >> 6, ln = t & 63;
  if (ln == 0) red[wv] = psum;
  accbuf[g][t & 31] = acc;
  __syncthreads();
  if (t < 32) {
    float4 a0 = accbuf[0][t], a1 = accbuf[1][t], a2 = accbuf[2][t], a3 = accbuf[3][t];
    float dn = red[0] + red[1];
    float inv = dn > 0.f ? 1.f / dn : 0.f;
    const float* bp = bias + t * 4;
    float4 r;
    r.x = (a0.x + a1.x + a2.x + a3.x) * inv + bp[0];
    r.y = (a0.y + a1.y + a2.y + a3.y) * inv + bp[1];
    r.z = (a0.z + a1.z + a2.z + a3.z) * inv + bp[2];
    r.w = (a0.w + a1.w + a2.w + a3.w) * inv + bp[3];
    *(float4*)&out[(size_t)n * 128 + t * 4] = r;
  }
}

// ---------------- mean-pool: 2-stage ----------------

__global__ void pool_partial_kernel(const float* __restrict__ h2, const int* __restrict__ gid,
                                    float* __restrict__ sums, int N) {
  int g = blockIdx.x / PSPLIT;
  int sp = blockIdx.x % PSPLIT;
  int tid = threadIdx.x;
  int lo0 = 0, hi0 = N;
  while (lo0 < hi0) { int m = (lo0 + hi0) >> 1; if (gid[m] < g) lo0 = m + 1; else hi0 = m; }
  int lo1 = lo0, hi1 = N;
  while (lo1 < hi1) { int m = (lo1 + hi1) >> 1; if (gid[m] < g + 1) lo1 = m + 1; else hi1 = m; }
  float a0 = 0.f, a1 = 0.f, a2 = 0.f, a3 = 0.f;
  int n = lo0 + sp;
  for (; n + 3 * PSPLIT < lo1; n += 4 * PSPLIT) {
    a0 += h2[(size_t)n * 128 + tid];
    a1 += h2[(size_t)(n + PSPLIT) * 128 + tid];
    a2 += h2[(size_t)(n + 2 * PSPLIT) * 128 + tid];
    a3 += h2[(size_t)(n + 3 * PSPLIT) * 128 + tid];
  }
  for (; n < lo1; n += PSPLIT) a0 += h2[(size_t)n * 128 + tid];
  float acc = (a0 + a1) + (a2 + a3);
  atomicAdd(&sums[g * 128 + tid], acc);
}

__global__ void pool_final_kernel(const float* __restrict__ sums, const int* __restrict__ gid,
                                  const float* __restrict__ linW, const float* __restrict__ linb,
                                  float* __restrict__ out, int N) {
  int g = blockIdx.x;
  int tid = threadIdx.x;
  int lo0 = 0, hi0 = N;
  while (lo0 < hi0) { int m = (lo0 + hi0) >> 1; if (gid[m] < g) lo0 = m + 1; else hi0 = m; }
  int lo1 = lo0, hi1 = N;
  while (lo1 < hi1) { int m = (lo1 + hi1) >> 1; if (gid[m] < g + 1) lo1 = m + 1; else hi1 = m; }
  int cnt = lo1 - lo0;
  float hg = sums[g * 128 + tid] / (float)(cnt > 0 ? cnt : 1);
  __shared__ float hgs[128];
  hgs[tid] = hg;
  __syncthreads();
  float o = linb[tid];
#pragma unroll 4
  for (int dd = 0; dd < 128; dd++) o += hgs[dd] * linW[dd * 128 + tid];
  out[g * 128 + tid] = fmaxf(o, 0.f);
}

// ---------------- launch ----------------

extern "C" void kernel_launch(void* const* d_in, const int* in_sizes, int n_in,
                              void* d_out, int out_size, void* d_ws, size_t ws_size,
                              hipStream_t stream) {
  const float* x    = (const float*)d_in[0];
  const int*   src  = (const int*)d_in[1];
  const int*   dst  = (const int*)d_in[2];
  const int*   gid  = (const int*)d_in[3];
  const float* W1   = (const float*)d_in[4];
  const float* al1  = (const float*)d_in[5];
  const float* ar1  = (const float*)d_in[6];
  const float* b1   = (const float*)d_in[7];
  const float* W2   = (const float*)d_in[8];
  const float* al2  = (const float*)d_in[9];
  const float* ar2  = (const float*)d_in[10];
  const float* b2   = (const float*)d_in[11];
  const float* linW = (const float*)d_in[12];
  const float* linb = (const float*)d_in[13];
  float* out = (float*)d_out;

  char* ws = (char*)d_ws;
  size_t off = 0;
  auto alloc = [&](size_t bytes) -> void* {
    void* p = ws + off;
    off += (bytes + 255) & ~(size_t)255;
    return p;
  };
  float* aggx    = (float*)alloc((size_t)NN * 384 * 4);
  float* h1      = (float*)alloc((size_t)NN * 384 * 4);
  float* f2      = (float*)alloc((size_t)NN * 128 * 4);
  float* h2      = (float*)alloc((size_t)NN * 128 * 4);
  float* el1     = (float*)alloc((size_t)NN * 3 * 4);
  float* er1     = (float*)alloc((size_t)NN * 3 * 4);
  float* wlr     = (float*)alloc((size_t)768 * 4);
  int*   loc     = (int*)alloc((size_t)NN * 4);
  int*   rowptr  = (int*)alloc((size_t)(NN + 1) * 4);
  int*   csr_src = (int*)alloc((size_t)NE * 4);
  int*   bsum    = (int*)alloc((size_t)NSCANB * 4);
  int*   boff    = (int*)alloc((size_t)NSCANB * 4);
  // zero-initialized region (single memset): el2, er2, indeg, cursor, gsums
  float* el2     = (float*)alloc((size_t)NN * 4);
  float* er2     = (float*)alloc((size_t)NN * 4);
  int*   indeg   = (int*)alloc((size_t)NN * 4);
  int*   cursor  = (int*)alloc((size_t)NN * 4);
  float* gsums   = (float*)alloc((size_t)NG * 128 * 4);
  (void)ws_size;
  size_t zbytes = (char*)(gsums + NG * 128) - (char*)el2;
  hipMemsetAsync(el2, 0, zbytes, stream);

  // CSR build + layer-1 attention coefs (packed)
  pack_hist_wlr_kernel<<<NHISTB + 3, 256, 0, stream>>>(dst, indeg, W1, al1, ar1, wlr);
  pack_scan1_elr_kernel<<<NSCANB + 5000, 256, 0, stream>>>(indeg, loc, bsum, x, wlr, el1, er1);
  scan2_kernel<<<1, 128, 0, stream>>>(bsum, boff, rowptr + NN, NSCANB);
  pack_scatter_fin_kernel<<<NHISTB + NSCANB, 256, 0, stream>>>(src, dst, loc, boff, cursor,
                                                               csr_src, rowptr);

  // Layer 1 (x-space): aggregate x -> per-head GEMM (K=128) with bias+ELU
  aggregate_x_kernel<<<NN, 128, 0, stream>>>(x, el1, er1, rowptr, csr_src, aggx);
  gemm_k128_kernel<128, true, true, false><<<dim3(625, 6), 128, 0, stream>>>(
      aggx, 384, W1, 384, h1, 384, b1, nullptr, nullptr, nullptr, nullptr);

  // Layer 2: f2 = h1 @ W2 (K=384) with fused el2/er2 epilogue; aggregate(+b2) -> h2
  gemm_k128_kernel<384, false, false, true><<<dim3(625, 2), 128, 0, stream>>>(
      h1, 384, W2, 128, f2, 128, nullptr, al2, ar2, el2, er2);
  aggregate1_kernel<<<NN, 128, 0, stream>>>(f2, el2, er2, b2, rowptr, csr_src, h2);

  // Mean-pool + linear head
  pool_partial_kernel<<<NG * PSPLIT, 128, 0, stream>>>(h2, gid, gsums, NN);
  pool_final_kernel<<<NG, 128, 0, stream>>>(gsums, gid, linW, linb, out, NN);
}